// Round 4
// baseline (457.986 us; speedup 1.0000x reference)
//
#include <hip/hip_runtime.h>

// TwoPlaneTensoRF: bilinear sample 2 x [128,512,512] planes at per-point 2D
// coords, channel-wise product, reduce 16 comps -> 8 out channels, sigmoid.
// OUTPUT IS FP32 (round 2/3 forensics: absmax bit-identical to the zero-stub
// => untouched fp32 tail; u16-addressed writes only covered half the buffer).
//
// Input dtypes sniffed at runtime on-device (1-block kernel votes on bit
// patterns, writes flags to d_ws; later kernels branch wave-uniformly).
//
// Pipeline: (1) sniff; (2) transpose planes [C,H,W] -> [H,W,C] bf16 in ws
// (one point's 128-ch gather becomes 4 contiguous 256B chunks per plane;
// both transposed planes = 128 MiB -> L3-resident); (3) one wave per point,
// lane l owns channels {2l,2l+1}, shfl_xor butterfly over lane bits 2..5
// reduces the 16 components, lanes 0..3 write float2 out-channel pairs.

#define N_PTS 524288
#define HH 512
#define WW 512
#define HWSZ (HH * WW)
#define CCH 128

typedef unsigned int u32;
typedef unsigned short u16;

__device__ __forceinline__ float b2f(u16 u) {
  union { u32 i; float f; } v; v.i = ((u32)u) << 16; return v.f;
}
__device__ __forceinline__ void unp2(u32 u, float& lo, float& hi) {
  union { u32 i; float f; } a, b;
  a.i = u << 16; b.i = u & 0xffff0000u;
  lo = a.f; hi = b.f;
}
__device__ __forceinline__ u16 f2b(float f) {
  union { float f; u32 i; } v; v.f = f;
  u32 r = v.i + 0x7fffu + ((v.i >> 16) & 1u);
  return (u16)(r >> 16);
}
__device__ __forceinline__ float sigmoidf(float v) {
  return 1.0f / (1.0f + __expf(-v));
}

// ---------------- dtype sniffer ----------------
// flags bit0: bounds bf16; bit1: x bf16; bit2: planes bf16.
// Vote on even-indexed u16s: if the buffer is fp32, those are fp32 low
// halves (mantissa bits ~uniform -> "exponent" rarely plausible, ~13%);
// if bf16, they are real values (plausible ~100%).
__global__ void sniff_kernel(const u16* __restrict__ x,
                             const u16* __restrict__ bnd,
                             const u16* __restrict__ uvp,
                             u32* __restrict__ flags) {
  if (threadIdx.x == 0 && blockIdx.x == 0) {
    u32 f = 0;
    // bounds = [0,0,0,0,1,1,1,1]. bf16: u32[2] = 0x3F80|0x3F80<<16.
    // fp32: u32[2] = bits of 0.0f = 0.
    if (((const u32*)bnd)[2] == 0x3F803F80u) f |= 1u;
    int cx = 0;
    for (int i = 0; i < 64; ++i) {          // x in (0.05,0.95): e in [121,126]
      int e = (x[2 * i] >> 7) & 0xFF;
      cx += (e >= 121 && e <= 126);
    }
    if (cx >= 32) f |= 2u;
    int cp = 0;
    for (int i = 0; i < 64; ++i) {          // plane vals ~ +-[1e-4, 2]
      int e = (uvp[2 * i] >> 7) & 0xFF;
      cp += (e >= 96 && e <= 128);
    }
    if (cp >= 32) f |= 4u;
    *flags = f;
  }
}

// ---------------- transpose [C, HW] -> [HW, C] bf16 ----------------
// grid: (HW/64, C/64, 2 planes), block 256. Tile 64(p) x 64(c).
__global__ __launch_bounds__(256) void transpose_planes(
    const void* __restrict__ uv, const void* __restrict__ st,
    u16* __restrict__ tuv, u16* __restrict__ tst,
    const u32* __restrict__ flags) {
  const bool pbf = ((*flags) >> 2) & 1;
  const void* __restrict__ src = blockIdx.z ? st : uv;
  u16* __restrict__ dst = blockIdx.z ? tst : tuv;
  __shared__ u16 tile[64][65];  // [p_local][c_local], +1 pad breaks conflicts
  const int p0 = blockIdx.x * 64;
  const int c0 = blockIdx.y * 64;
  const int tx = threadIdx.x & 31;   // p-pair (load) / c-pair (store) index
  const int ty = threadIdx.x >> 5;   // 0..7
  if (pbf) {
    const u16* s = (const u16*)src;
#pragma unroll
    for (int it = 0; it < 8; ++it) {
      int cl = ty + 8 * it;
      u32 v = *(const u32*)(s + (size_t)(c0 + cl) * HWSZ + p0 + 2 * tx);
      tile[2 * tx][cl] = (u16)(v & 0xffffu);
      tile[2 * tx + 1][cl] = (u16)(v >> 16);
    }
  } else {
    const float* s = (const float*)src;
#pragma unroll
    for (int it = 0; it < 8; ++it) {
      int cl = ty + 8 * it;
      float2 v = *(const float2*)(s + (size_t)(c0 + cl) * HWSZ + p0 + 2 * tx);
      tile[2 * tx][cl] = f2b(v.x);
      tile[2 * tx + 1][cl] = f2b(v.y);
    }
  }
  __syncthreads();
#pragma unroll
  for (int it = 0; it < 8; ++it) {
    int pl = ty + 8 * it;
    u32 v = (u32)tile[pl][2 * tx] | ((u32)tile[pl][2 * tx + 1] << 16);
    *(u32*)(dst + (size_t)(p0 + pl) * CCH + c0 + 2 * tx) = v;
  }
}

// ---------------- wave-per-point gather from [H,W,C] bf16 ----------------
__global__ __launch_bounds__(256) void gather_points(
    const void* __restrict__ xc, const u16* __restrict__ tuv,
    const u16* __restrict__ tst, const void* __restrict__ bnd,
    float* __restrict__ out, const u32* __restrict__ flags) {
  const u32 fl = *flags;
  const int lane = threadIdx.x & 63;
  const int p = blockIdx.x * 4 + (threadIdx.x >> 6);

  float f0, f1, f2, f3, lo0, lo1, lo2, lo3, hi0, hi1, hi2, hi3;
  if (fl & 2u) {
    const u16* xp = (const u16*)xc + (size_t)p * 4;
    f0 = b2f(xp[0]); f1 = b2f(xp[1]); f2 = b2f(xp[2]); f3 = b2f(xp[3]);
  } else {
    const float* xp = (const float*)xc + (size_t)p * 4;
    f0 = xp[0]; f1 = xp[1]; f2 = xp[2]; f3 = xp[3];
  }
  if (fl & 1u) {
    const u16* b = (const u16*)bnd;
    lo0 = b2f(b[0]); lo1 = b2f(b[1]); lo2 = b2f(b[2]); lo3 = b2f(b[3]);
    hi0 = b2f(b[4]); hi1 = b2f(b[5]); hi2 = b2f(b[6]); hi3 = b2f(b[7]);
  } else {
    const float* b = (const float*)bnd;
    lo0 = b[0]; lo1 = b[1]; lo2 = b[2]; lo3 = b[3];
    hi0 = b[4]; hi1 = b[5]; hi2 = b[6]; hi3 = b[7];
  }

  // ix = (norm+1)/2*(W-1) = (x-lo)/(hi-lo)*(W-1), align_corners=True
  const float ixu = (f0 - lo0) / (hi0 - lo0) * 511.0f;
  const float iyu = (f1 - lo1) / (hi1 - lo1) * 511.0f;
  const float ixs = (f2 - lo2) / (hi2 - lo2) * 511.0f;
  const float iys = (f3 - lo3) / (hi3 - lo3) * 511.0f;

  int x0u = min(max((int)floorf(ixu), 0), WW - 2); const float wxu = ixu - (float)x0u;
  int y0u = min(max((int)floorf(iyu), 0), HH - 2); const float wyu = iyu - (float)y0u;
  int x0s = min(max((int)floorf(ixs), 0), WW - 2); const float wxs = ixs - (float)x0s;
  int y0s = min(max((int)floorf(iys), 0), HH - 2); const float wys = iys - (float)y0s;

  // lane l holds channels 2l, 2l+1 (one u32 = 2 bf16) per corner
  const size_t bu = (size_t)(y0u * WW + x0u) * CCH + 2 * lane;
  const size_t bs = (size_t)(y0s * WW + x0s) * CCH + 2 * lane;

  const u32 ua = *(const u32*)(tuv + bu);
  const u32 ub = *(const u32*)(tuv + bu + CCH);
  const u32 uc = *(const u32*)(tuv + bu + (size_t)WW * CCH);
  const u32 ud = *(const u32*)(tuv + bu + (size_t)WW * CCH + CCH);
  const u32 sa = *(const u32*)(tst + bs);
  const u32 sb = *(const u32*)(tst + bs + CCH);
  const u32 sc = *(const u32*)(tst + bs + (size_t)WW * CCH);
  const u32 sd = *(const u32*)(tst + bs + (size_t)WW * CCH + CCH);

  float a0, a1, b0, b1, c0, c1, d0, d1;
  unp2(ua, a0, a1); unp2(ub, b0, b1); unp2(uc, c0, c1); unp2(ud, d0, d1);
  float t0 = a0 + (b0 - a0) * wxu, t1 = a1 + (b1 - a1) * wxu;
  float q0 = c0 + (d0 - c0) * wxu, q1 = c1 + (d1 - c1) * wxu;
  const float uv0 = t0 + (q0 - t0) * wyu, uv1 = t1 + (q1 - t1) * wyu;

  unp2(sa, a0, a1); unp2(sb, b0, b1); unp2(sc, c0, c1); unp2(sd, d0, d1);
  t0 = a0 + (b0 - a0) * wxs; t1 = a1 + (b1 - a1) * wxs;
  q0 = c0 + (d0 - c0) * wxs; q1 = c1 + (d1 - c1) * wxs;
  const float st0 = t0 + (q0 - t0) * wys, st1 = t1 + (q1 - t1) * wys;

  float pr0 = uv0 * st0;
  float pr1 = uv1 * st1;

  // channel c=2l -> out ch 2*(l%4); c=2l+1 -> 2*(l%4)+1. Reduce lane bits 2..5.
#pragma unroll
  for (int m = 4; m < 64; m <<= 1) {
    pr0 += __shfl_xor(pr0, m, 64);
    pr1 += __shfl_xor(pr1, m, 64);
  }

  if (lane < 4) {
    float2 s;
    s.x = sigmoidf(pr0);
    s.y = sigmoidf(pr1);
    *(float2*)(out + (size_t)p * 8 + 2 * lane) = s;
  }
}

// ------- fallback: direct gather from [C,H,W] (only if ws too small) -------
__global__ __launch_bounds__(256) void direct_points(
    const void* __restrict__ xc, const void* __restrict__ uv,
    const void* __restrict__ st, const void* __restrict__ bnd,
    float* __restrict__ out, const u32* __restrict__ flags) {
  const u32 fl = *flags;
  const int p = blockIdx.x * blockDim.x + threadIdx.x;
  if (p >= N_PTS) return;
  float f0, f1, f2, f3, lo[4], hi[4];
  if (fl & 2u) {
    const u16* xp = (const u16*)xc + (size_t)p * 4;
    f0 = b2f(xp[0]); f1 = b2f(xp[1]); f2 = b2f(xp[2]); f3 = b2f(xp[3]);
  } else {
    const float* xp = (const float*)xc + (size_t)p * 4;
    f0 = xp[0]; f1 = xp[1]; f2 = xp[2]; f3 = xp[3];
  }
  for (int j = 0; j < 4; ++j) {
    if (fl & 1u) { lo[j] = b2f(((const u16*)bnd)[j]); hi[j] = b2f(((const u16*)bnd)[4 + j]); }
    else { lo[j] = ((const float*)bnd)[j]; hi[j] = ((const float*)bnd)[4 + j]; }
  }
  const float ixu = (f0 - lo[0]) / (hi[0] - lo[0]) * 511.0f;
  const float iyu = (f1 - lo[1]) / (hi[1] - lo[1]) * 511.0f;
  const float ixs = (f2 - lo[2]) / (hi[2] - lo[2]) * 511.0f;
  const float iys = (f3 - lo[3]) / (hi[3] - lo[3]) * 511.0f;
  int x0u = min(max((int)floorf(ixu), 0), WW - 2); const float wxu = ixu - (float)x0u;
  int y0u = min(max((int)floorf(iyu), 0), HH - 2); const float wyu = iyu - (float)y0u;
  int x0s = min(max((int)floorf(ixs), 0), WW - 2); const float wxs = ixs - (float)x0s;
  int y0s = min(max((int)floorf(iys), 0), HH - 2); const float wys = iys - (float)y0s;
  const size_t ou = (size_t)y0u * WW + x0u;
  const size_t os = (size_t)y0s * WW + x0s;
  const bool pbf = (fl >> 2) & 1;
  float acc[8];
#pragma unroll
  for (int j = 0; j < 8; ++j) acc[j] = 0.0f;
  for (int c = 0; c < CCH; ++c) {
    float u00, u01, u10, u11, s00, s01, s10, s11;
    if (pbf) {
      const u16* pu = (const u16*)uv + (size_t)c * HWSZ + ou;
      u00 = b2f(pu[0]); u01 = b2f(pu[1]); u10 = b2f(pu[WW]); u11 = b2f(pu[WW + 1]);
      const u16* ps = (const u16*)st + (size_t)c * HWSZ + os;
      s00 = b2f(ps[0]); s01 = b2f(ps[1]); s10 = b2f(ps[WW]); s11 = b2f(ps[WW + 1]);
    } else {
      const float* pu = (const float*)uv + (size_t)c * HWSZ + ou;
      u00 = pu[0]; u01 = pu[1]; u10 = pu[WW]; u11 = pu[WW + 1];
      const float* ps = (const float*)st + (size_t)c * HWSZ + os;
      s00 = ps[0]; s01 = ps[1]; s10 = ps[WW]; s11 = ps[WW + 1];
    }
    float t = u00 + (u01 - u00) * wxu;
    float b = u10 + (u11 - u10) * wxu;
    const float uvv = t + (b - t) * wyu;
    t = s00 + (s01 - s00) * wxs;
    b = s10 + (s11 - s10) * wxs;
    const float stv = t + (b - t) * wys;
    acc[c & 7] += uvv * stv;
  }
#pragma unroll
  for (int j = 0; j < 8; ++j) out[(size_t)p * 8 + j] = sigmoidf(acc[j]);
}

extern "C" void kernel_launch(void* const* d_in, const int* in_sizes, int n_in,
                              void* d_out, int out_size, void* d_ws, size_t ws_size,
                              hipStream_t stream) {
  const void* xc = d_in[0];
  const void* uv = d_in[1];
  const void* st = d_in[2];
  const void* bnd = d_in[3];
  float* out = (float*)d_out;

  const size_t plane_elems = (size_t)CCH * HWSZ;                 // 33,554,432
  const size_t need = 2 * plane_elems * sizeof(u16) + 16;        // 128 MiB + flags

  if (ws_size >= need) {
    u16* tuv = (u16*)d_ws;
    u16* tst = tuv + plane_elems;
    u32* flags = (u32*)(tst + plane_elems);
    sniff_kernel<<<1, 64, 0, stream>>>((const u16*)xc, (const u16*)bnd,
                                       (const u16*)uv, flags);
    dim3 tg(HWSZ / 64, CCH / 64, 2);
    transpose_planes<<<tg, 256, 0, stream>>>(uv, st, tuv, tst, flags);
    gather_points<<<N_PTS / 4, 256, 0, stream>>>(xc, tuv, tst, bnd, out, flags);
  } else {
    u32* flags = (u32*)d_ws;  // ws is at least a few bytes
    sniff_kernel<<<1, 64, 0, stream>>>((const u16*)xc, (const u16*)bnd,
                                       (const u16*)uv, flags);
    direct_points<<<(N_PTS + 255) / 256, 256, 0, stream>>>(xc, uv, st, bnd, out, flags);
  }
}

// Round 5
// 440.425 us; speedup vs baseline: 1.0399x; 1.0399x over previous
//
#include <hip/hip_runtime.h>

// TwoPlaneTensoRF: bilinear sample 2 x [128,512,512] planes at per-point 2D
// coords, channel-wise product, reduce 16 comps -> 8 out channels, sigmoid.
// Output fp32 (round-3 forensics). Inputs almost certainly fp32; each kernel
// does a cheap wave-parallel dtype vote anyway (wave-uniform branch).
//
// R4 counters: gather VALUBusy=117% (VALU-paced), 40% HBM; sniff kernel was
// 1-thread serial (~whole-GPU idle). This round: inline detection (no sniff
// dispatch), float4-wide transpose, and 2-points-per-wave gather (half the
// waves, v_rcp instead of div, lane owns 4 channels via dwordx2).

#define HH 512
#define WW 512
#define HWSZ (HH * WW)
#define CCH 128
#define P32 134  // u32 LDS pitch: b64-aligned writes, 4-way-max read conflicts

typedef unsigned int u32;
typedef unsigned short u16;
typedef unsigned long long u64;

__device__ __forceinline__ float b2f(u16 u) {
  union { u32 i; float f; } v; v.i = ((u32)u) << 16; return v.f;
}
__device__ __forceinline__ void unp2(u32 u, float& lo, float& hi) {
  union { u32 i; float f; } a, b;
  a.i = u << 16; b.i = u & 0xffff0000u;
  lo = a.f; hi = b.f;
}
__device__ __forceinline__ u16 f2b(float f) {  // RNE fp32->bf16
  union { float f; u32 i; } v; v.f = f;
  u32 r = v.i + 0x7fffu + ((v.i >> 16) & 1u);
  return (u16)(r >> 16);
}
__device__ __forceinline__ float sigmoidf(float v) {
  return 1.0f / (1.0f + __expf(-v));
}

// wave-parallel dtype vote: sample even u16s; fp32 low-halves are ~uniform
// bits (exponent field rarely plausible); bf16 reals are ~always plausible.
__device__ __forceinline__ bool vote_bf16(const u16* buf, int lane, int e_lo, int e_hi) {
  int e = (buf[2 * lane] >> 7) & 0xFF;
  u64 bal = __ballot(e >= e_lo && e <= e_hi);
  return __popcll(bal) >= 32;
}

// ---------------- transpose [C,H,W] -> [H,W,C] bf16 ----------------
// block 256 = 8 half-waves; tile = all 128 channels x 128 points.
// grid: (HWSZ/128, 1, 2 planes).
__global__ __launch_bounds__(256) void transpose_planes(
    const void* __restrict__ uv, const void* __restrict__ st,
    u32* __restrict__ tuv32, u32* __restrict__ tst32) {
  const void* __restrict__ src = blockIdx.z ? st : uv;
  u32* __restrict__ dst = blockIdx.z ? tst32 : tuv32;
  __shared__ u32 tile[64][P32];  // [channel-pair][point]
  const int p0 = blockIdx.x * 128;
  const int tx = threadIdx.x & 31;
  const int ty = threadIdx.x >> 5;  // 0..7
  const int lane = threadIdx.x & 63;

  const bool pbf = vote_bf16((const u16*)src, lane, 96, 128);

  if (pbf) {
    const u16* s = (const u16*)src;
#pragma unroll
    for (int it = 0; it < 8; ++it) {
      const int cp = ty + 8 * it;  // channel pair 0..63
      const u16* rA = s + (size_t)(2 * cp) * HWSZ + p0 + 4 * tx;
      const u16* rB = rA + HWSZ;
      ushort4 a = *(const ushort4*)rA;  // 8B: 4 points of ch 2cp
      ushort4 b = *(const ushort4*)rB;  // 4 points of ch 2cp+1
      uint2 w01, w23;
      w01.x = (u32)a.x | ((u32)b.x << 16);
      w01.y = (u32)a.y | ((u32)b.y << 16);
      w23.x = (u32)a.z | ((u32)b.z << 16);
      w23.y = (u32)a.w | ((u32)b.w << 16);
      *(uint2*)&tile[cp][4 * tx] = w01;
      *(uint2*)&tile[cp][4 * tx + 2] = w23;
    }
  } else {
    const float* s = (const float*)src;
#pragma unroll
    for (int it = 0; it < 8; ++it) {
      const int cp = ty + 8 * it;
      const float* rA = s + (size_t)(2 * cp) * HWSZ + p0 + 4 * tx;
      const float* rB = rA + HWSZ;
      float4 a = *(const float4*)rA;  // 16B: 4 points of ch 2cp
      float4 b = *(const float4*)rB;  // 4 points of ch 2cp+1
      uint2 w01, w23;
      w01.x = (u32)f2b(a.x) | ((u32)f2b(b.x) << 16);
      w01.y = (u32)f2b(a.y) | ((u32)f2b(b.y) << 16);
      w23.x = (u32)f2b(a.z) | ((u32)f2b(b.z) << 16);
      w23.y = (u32)f2b(a.w) | ((u32)f2b(b.w) << 16);
      *(uint2*)&tile[cp][4 * tx] = w01;
      *(uint2*)&tile[cp][4 * tx + 2] = w23;
    }
  }
  __syncthreads();
  // store: one full [H,W,C] row (128 ch = 64 u32 = 256B) per half-wave
#pragma unroll
  for (int it = 0; it < 16; ++it) {
    const int pl = ty + 8 * it;  // 0..127
    uint2 w;
    w.x = tile[2 * tx][pl];
    w.y = tile[2 * tx + 1][pl];
    *(uint2*)(dst + (size_t)(p0 + pl) * (CCH / 2) + 2 * tx) = w;
  }
}

// ---------------- gather: 2 points per wave ----------------
// lane il=lane&31 owns channels 4il..4il+3 of point (blockIdx*8 + tid>>5).
// comp n = il>>1; out o = (il&1)*4 + j. Reduce over n: shfl_xor {2,4,8,16}.
__global__ __launch_bounds__(256) void gather_points(
    const void* __restrict__ xc, const u16* __restrict__ tuv,
    const u16* __restrict__ tst, const void* __restrict__ bnd,
    float* __restrict__ out, int n) {
  const int lane = threadIdx.x & 63;
  const int il = threadIdx.x & 31;
  int p = blockIdx.x * 8 + (threadIdx.x >> 5);
  p = min(p, n - 1);

  const bool xbf = vote_bf16((const u16*)xc, lane, 121, 126);
  const bool bbf = (((const u32*)bnd)[2] == 0x3F803F80u);

  float f0, f1, f2, f3, lo0, lo1, lo2, lo3, hi0, hi1, hi2, hi3;
  if (xbf) {
    const u16* xp = (const u16*)xc + (size_t)p * 4;
    f0 = b2f(xp[0]); f1 = b2f(xp[1]); f2 = b2f(xp[2]); f3 = b2f(xp[3]);
  } else {
    const float4 c = *(const float4*)((const float*)xc + (size_t)p * 4);
    f0 = c.x; f1 = c.y; f2 = c.z; f3 = c.w;
  }
  if (bbf) {
    const u16* b = (const u16*)bnd;
    lo0 = b2f(b[0]); lo1 = b2f(b[1]); lo2 = b2f(b[2]); lo3 = b2f(b[3]);
    hi0 = b2f(b[4]); hi1 = b2f(b[5]); hi2 = b2f(b[6]); hi3 = b2f(b[7]);
  } else {
    const float* b = (const float*)bnd;
    lo0 = b[0]; lo1 = b[1]; lo2 = b[2]; lo3 = b[3];
    hi0 = b[4]; hi1 = b[5]; hi2 = b[6]; hi3 = b[7];
  }

  // ix = (x-lo)/(hi-lo)*(W-1); v_rcp (1ulp) instead of 4 full divides
  const float ixu = (f0 - lo0) * __builtin_amdgcn_rcpf(hi0 - lo0) * 511.0f;
  const float iyu = (f1 - lo1) * __builtin_amdgcn_rcpf(hi1 - lo1) * 511.0f;
  const float ixs = (f2 - lo2) * __builtin_amdgcn_rcpf(hi2 - lo2) * 511.0f;
  const float iys = (f3 - lo3) * __builtin_amdgcn_rcpf(hi3 - lo3) * 511.0f;

  int x0u = min(max((int)floorf(ixu), 0), WW - 2); const float wxu = ixu - (float)x0u;
  int y0u = min(max((int)floorf(iyu), 0), HH - 2); const float wyu = iyu - (float)y0u;
  int x0s = min(max((int)floorf(ixs), 0), WW - 2); const float wxs = ixs - (float)x0s;
  int y0s = min(max((int)floorf(iys), 0), HH - 2); const float wys = iys - (float)y0s;

  // lane owns 4 channels = 8B per corner; 4 corners x 2 planes = 8 dwordx2
  const size_t bu = (size_t)(y0u * WW + x0u) * CCH + 4 * il;
  const size_t bs = (size_t)(y0s * WW + x0s) * CCH + 4 * il;

  const uint2 u00 = *(const uint2*)(tuv + bu);
  const uint2 u01 = *(const uint2*)(tuv + bu + CCH);
  const uint2 u10 = *(const uint2*)(tuv + bu + (size_t)WW * CCH);
  const uint2 u11 = *(const uint2*)(tuv + bu + (size_t)WW * CCH + CCH);
  const uint2 s00 = *(const uint2*)(tst + bs);
  const uint2 s01 = *(const uint2*)(tst + bs + CCH);
  const uint2 s10 = *(const uint2*)(tst + bs + (size_t)WW * CCH);
  const uint2 s11 = *(const uint2*)(tst + bs + (size_t)WW * CCH + CCH);

  float pr[4];
  {
    float a0, a1, a2, a3, b0, b1, b2, b3, c0, c1, c2, c3, d0, d1, d2, d3;
    unp2(u00.x, a0, a1); unp2(u00.y, a2, a3);
    unp2(u01.x, b0, b1); unp2(u01.y, b2, b3);
    unp2(u10.x, c0, c1); unp2(u10.y, c2, c3);
    unp2(u11.x, d0, d1); unp2(u11.y, d2, d3);
    const float t0 = a0 + (b0 - a0) * wxu, t1 = a1 + (b1 - a1) * wxu;
    const float t2 = a2 + (b2 - a2) * wxu, t3 = a3 + (b3 - a3) * wxu;
    const float q0 = c0 + (d0 - c0) * wxu, q1 = c1 + (d1 - c1) * wxu;
    const float q2 = c2 + (d2 - c2) * wxu, q3 = c3 + (d3 - c3) * wxu;
    pr[0] = t0 + (q0 - t0) * wyu; pr[1] = t1 + (q1 - t1) * wyu;
    pr[2] = t2 + (q2 - t2) * wyu; pr[3] = t3 + (q3 - t3) * wyu;
  }
  {
    float a0, a1, a2, a3, b0, b1, b2, b3, c0, c1, c2, c3, d0, d1, d2, d3;
    unp2(s00.x, a0, a1); unp2(s00.y, a2, a3);
    unp2(s01.x, b0, b1); unp2(s01.y, b2, b3);
    unp2(s10.x, c0, c1); unp2(s10.y, c2, c3);
    unp2(s11.x, d0, d1); unp2(s11.y, d2, d3);
    const float t0 = a0 + (b0 - a0) * wxs, t1 = a1 + (b1 - a1) * wxs;
    const float t2 = a2 + (b2 - a2) * wxs, t3 = a3 + (b3 - a3) * wxs;
    const float q0 = c0 + (d0 - c0) * wxs, q1 = c1 + (d1 - c1) * wxs;
    const float q2 = c2 + (d2 - c2) * wxs, q3 = c3 + (d3 - c3) * wxs;
    pr[0] *= t0 + (q0 - t0) * wys; pr[1] *= t1 + (q1 - t1) * wys;
    pr[2] *= t2 + (q2 - t2) * wys; pr[3] *= t3 + (q3 - t3) * wys;
  }

  // reduce comps (il>>1) within each 32-lane half
#pragma unroll
  for (int m = 2; m <= 16; m <<= 1) {
#pragma unroll
    for (int j = 0; j < 4; ++j) pr[j] += __shfl_xor(pr[j], m, 64);
  }

  if (il < 2) {
    float4 s;
    s.x = sigmoidf(pr[0]); s.y = sigmoidf(pr[1]);
    s.z = sigmoidf(pr[2]); s.w = sigmoidf(pr[3]);
    *(float4*)(out + (size_t)p * 8 + il * 4) = s;
  }
}

// ------- fallback: direct fp32 gather from [C,H,W] (ws too small) -------
__global__ __launch_bounds__(256) void direct_points(
    const float* __restrict__ xc, const float* __restrict__ uv,
    const float* __restrict__ st, const float* __restrict__ bnd,
    float* __restrict__ out, int n) {
  const int p = blockIdx.x * blockDim.x + threadIdx.x;
  if (p >= n) return;
  const float* xp = xc + (size_t)p * 4;
  const float ixu = (xp[0] - bnd[0]) / (bnd[4] - bnd[0]) * 511.0f;
  const float iyu = (xp[1] - bnd[1]) / (bnd[5] - bnd[1]) * 511.0f;
  const float ixs = (xp[2] - bnd[2]) / (bnd[6] - bnd[2]) * 511.0f;
  const float iys = (xp[3] - bnd[3]) / (bnd[7] - bnd[3]) * 511.0f;
  int x0u = min(max((int)floorf(ixu), 0), WW - 2); const float wxu = ixu - (float)x0u;
  int y0u = min(max((int)floorf(iyu), 0), HH - 2); const float wyu = iyu - (float)y0u;
  int x0s = min(max((int)floorf(ixs), 0), WW - 2); const float wxs = ixs - (float)x0s;
  int y0s = min(max((int)floorf(iys), 0), HH - 2); const float wys = iys - (float)y0s;
  const size_t ou = (size_t)y0u * WW + x0u;
  const size_t os = (size_t)y0s * WW + x0s;
  float acc[8];
#pragma unroll
  for (int j = 0; j < 8; ++j) acc[j] = 0.0f;
  for (int c = 0; c < CCH; ++c) {
    const float* pu = uv + (size_t)c * HWSZ + ou;
    float t = pu[0] + (pu[1] - pu[0]) * wxu;
    float b = pu[WW] + (pu[WW + 1] - pu[WW]) * wxu;
    const float uvv = t + (b - t) * wyu;
    const float* ps = st + (size_t)c * HWSZ + os;
    t = ps[0] + (ps[1] - ps[0]) * wxs;
    b = ps[WW] + (ps[WW + 1] - ps[WW]) * wxs;
    const float stv = t + (b - t) * wys;
    acc[c & 7] += uvv * stv;
  }
#pragma unroll
  for (int j = 0; j < 8; ++j) out[(size_t)p * 8 + j] = sigmoidf(acc[j]);
}

extern "C" void kernel_launch(void* const* d_in, const int* in_sizes, int n_in,
                              void* d_out, int out_size, void* d_ws, size_t ws_size,
                              hipStream_t stream) {
  const void* xc = d_in[0];
  const void* uv = d_in[1];
  const void* st = d_in[2];
  const void* bnd = d_in[3];
  float* out = (float*)d_out;
  const int n = in_sizes[0] / 4;

  const size_t plane_elems = (size_t)CCH * HWSZ;          // 33,554,432
  const size_t need = 2 * plane_elems * sizeof(u16);      // 128 MiB

  if (ws_size >= need) {
    u16* tuv = (u16*)d_ws;
    u16* tst = tuv + plane_elems;
    dim3 tg(HWSZ / 128, 1, 2);
    transpose_planes<<<tg, 256, 0, stream>>>(uv, st, (u32*)tuv, (u32*)tst);
    gather_points<<<(n + 7) / 8, 256, 0, stream>>>(xc, tuv, tst, bnd, out, n);
  } else {
    direct_points<<<(n + 255) / 256, 256, 0, stream>>>(
        (const float*)xc, (const float*)uv, (const float*)st,
        (const float*)bnd, out, n);
  }
}